// Round 1
// baseline (343133.008 us; speedup 1.0000x reference)
//
#include <hip/hip_runtime.h>
#include <math.h>

#define B    32
#define S    2048
#define DIN  256
#define H    512
#define G    2048   // 4H
#define DOUT 256
#define BH   (B*H)

__device__ __forceinline__ float sigf(float v) { return 1.0f / (1.0f + expf(-v)); }

// Stage a [B][cs] fp32 panel into LDS (cs = 1<<cs_bits), coalesced along k.
__device__ __forceinline__ void stage_lds(float* dst, const float* __restrict__ src,
                                          long rstride, int cs_bits, int tid)
{
    const int cs  = 1 << cs_bits;
    const int tot = B << cs_bits;
    for (int idx = tid; idx < tot; idx += 256) {
        const int r  = idx >> cs_bits;
        const int kk = idx & (cs - 1);
        dst[idx] = src[(long)r * rstride + kk];
    }
}

// acc two rows (r0, r0+16) x one column over a K-chunk staged in LDS.
__device__ __forceinline__ void fma_chunk(const float* __restrict__ Alds, int cs_bits,
                                          const float* __restrict__ W, long wstride, int col,
                                          int r0, float& a0, float& a1)
{
    const int cs = 1 << cs_bits;
    const float* wp  = W + col;
    const float* ar0 = Alds + ((long)r0 << cs_bits);
    const float* ar1 = Alds + ((long)(r0 + 16) << cs_bits);
    #pragma unroll 8
    for (int kk = 0; kk < cs; ++kk) {
        const float w = wp[(long)kk * wstride];
        a0 = fmaf(ar0[kk], w, a0);
        a1 = fmaf(ar1[kk], w, a1);
    }
}

// One pipeline phase k:
//   blocks [0,128)   : layer0, t = k      (4 h-cols each)
//   blocks [128,256) : layer1, t = k-1    (4 h-cols each)
//   blocks [256,272) : (fallback only) output FC for t = k-2, 16 cols each
// ws layout (floats): h0[2][B][H] | h1[2][B][H] | c0[B][H] | c1[B][H] | h1hist[B][S][H]
__global__ __launch_bounds__(256) void lstm_phase(
    const float* __restrict__ x,
    const float* __restrict__ Wx0, const float* __restrict__ bx0,
    const float* __restrict__ Wh0, const float* __restrict__ bh0,
    const float* __restrict__ Wx1, const float* __restrict__ bx1,
    const float* __restrict__ Wh1, const float* __restrict__ bh1,
    const float* __restrict__ Wfc, const float* __restrict__ bfc,
    float* __restrict__ out, float* __restrict__ ws, int k, int use_hist)
{
    float* h0s  = ws;
    float* h1s  = ws + 2*BH;
    float* c0s  = ws + 4*BH;
    float* c1s  = ws + 5*BH;
    float* hist = ws + 6*BH;

    __shared__ float Alds[B * 512];           // 64 KB, also reused as gate-exchange buffer
    float* glds = Alds;                       // [32][16] region reused after FMA chunks

    const int blk = blockIdx.x;
    const int tid = threadIdx.x;
    const int c   = tid & 15;
    const int r0  = tid >> 4;                 // 0..15 (rows r0 and r0+16)
    float a0 = 0.f, a1 = 0.f;

    if (blk < 256) {
        const bool L1 = (blk >= 128);
        const int  t  = L1 ? (k - 1) : k;
        if (t < 0 || t >= S) return;
        const int hb   = (L1 ? blk - 128 : blk) << 2;   // base h-col (4 per block)
        const int gate = c >> 2, sub = c & 3;           // f,i,g,o x 4 sub-cols
        const int gcol = gate * H + hb + sub;

        const float *sA0, *sA1, *W0, *W1, *bx, *bh;
        long rs0; int cb0;
        if (!L1) {
            sA0 = x + (size_t)t * DIN; rs0 = (long)S * DIN; cb0 = 8; W0 = Wx0;
            sA1 = h0s + ((t - 1) & 1) * BH;                          W1 = Wh0;
            bx = bx0; bh = bh0;
        } else {
            sA0 = h0s + (t & 1) * BH;  rs0 = H;           cb0 = 9;  W0 = Wx1;
            sA1 = h1s + ((t - 1) & 1) * BH;                          W1 = Wh1;
            bx = bx1; bh = bh1;
        }

        stage_lds(Alds, sA0, rs0, cb0, tid);
        __syncthreads();
        fma_chunk(Alds, cb0, W0, G, gcol, r0, a0, a1);
        __syncthreads();
        stage_lds(Alds, sA1, H, 9, tid);
        __syncthreads();
        fma_chunk(Alds, 9, W1, G, gcol, r0, a0, a1);
        __syncthreads();                                  // done reading Alds

        const float bias = bx[gcol] + bh[gcol];
        glds[r0 * 16 + c]        = a0 + bias;
        glds[(r0 + 16) * 16 + c] = a1 + bias;
        __syncthreads();

        if (tid < 128) {
            const int r = tid >> 2, s2 = tid & 3;
            const float f = glds[r * 16 + 0  + s2];
            const float i = glds[r * 16 + 4  + s2];
            const float g = glds[r * 16 + 8  + s2];
            const float o = glds[r * 16 + 12 + s2];
            const int j = hb + s2;
            float* cst = (L1 ? c1s : c0s) + r * H + j;
            const float cn = sigf(f) * (*cst) + sigf(i) * tanhf(g);
            const float hn = sigf(o) * tanhf(cn);
            *cst = cn;
            (L1 ? h1s : h0s)[(t & 1) * BH + r * H + j] = hn;
            if (L1 && use_hist) hist[((size_t)r * S + t) * H + j] = hn;
        }
        return;
    }

    // ---- fallback in-phase FC (only launched when ws too small for history) ----
    {
        const int t = k - 2;
        if (t < 0 || t >= S) return;
        const int col = ((blk - 256) << 4) + c;
        stage_lds(Alds, h1s + (t & 1) * BH, H, 9, tid);
        __syncthreads();
        fma_chunk(Alds, 9, Wfc, DOUT, col, r0, a0, a1);
        const float bias = bfc[col];
        out[((size_t)r0 * S + t) * DOUT + col]        = a0 + bias;
        out[((size_t)(r0 + 16) * S + t) * DOUT + col] = a1 + bias;
    }
}

// Final projection: out[B*S, DOUT] = h1hist[B*S, H] @ Wfc[H, DOUT] + bfc
__global__ __launch_bounds__(256) void fc_kernel(
    const float* __restrict__ A, const float* __restrict__ Wfc,
    const float* __restrict__ bfc, float* __restrict__ out)
{
    __shared__ float As[64][65];
    __shared__ float Wsh[64][65];
    const int rb  = blockIdx.x * 64;
    const int cb  = blockIdx.y * 64;
    const int tid = threadIdx.x;
    const int tr  = tid >> 4, tc = tid & 15;
    float acc[4][4] = {};
    for (int k0 = 0; k0 < H; k0 += 64) {
        for (int idx = tid; idx < 64 * 64; idx += 256) {
            const int r = idx >> 6, kk = idx & 63;
            As[r][kk]  = A[(size_t)(rb + r) * H + k0 + kk];
            Wsh[r][kk] = Wfc[(size_t)(k0 + r) * DOUT + cb + kk];  // Wsh[krow][col]
        }
        __syncthreads();
        #pragma unroll 16
        for (int kk = 0; kk < 64; ++kk) {
            float av[4], wv[4];
            #pragma unroll
            for (int i = 0; i < 4; ++i) av[i] = As[tr * 4 + i][kk];
            #pragma unroll
            for (int j = 0; j < 4; ++j) wv[j] = Wsh[kk][tc * 4 + j];
            #pragma unroll
            for (int i = 0; i < 4; ++i)
                #pragma unroll
                for (int j = 0; j < 4; ++j)
                    acc[i][j] = fmaf(av[i], wv[j], acc[i][j]);
        }
        __syncthreads();
    }
    #pragma unroll
    for (int i = 0; i < 4; ++i) {
        const size_t r = rb + tr * 4 + i;
        #pragma unroll
        for (int j = 0; j < 4; ++j) {
            const int cc = cb + tc * 4 + j;
            out[r * DOUT + cc] = acc[i][j] + bfc[cc];
        }
    }
}

extern "C" void kernel_launch(void* const* d_in, const int* in_sizes, int n_in,
                              void* d_out, int out_size, void* d_ws, size_t ws_size,
                              hipStream_t stream)
{
    const float* x   = (const float*)d_in[0];
    const float* Wx0 = (const float*)d_in[1];
    const float* bx0 = (const float*)d_in[2];
    const float* Wh0 = (const float*)d_in[3];
    const float* bh0 = (const float*)d_in[4];
    const float* Wx1 = (const float*)d_in[5];
    const float* bx1 = (const float*)d_in[6];
    const float* Wh1 = (const float*)d_in[7];
    const float* bh1 = (const float*)d_in[8];
    const float* Wfc = (const float*)d_in[9];
    const float* bfc = (const float*)d_in[10];
    float* out = (float*)d_out;
    float* ws  = (float*)d_ws;

    const size_t need_hist = ((size_t)6 * BH + (size_t)B * S * H) * sizeof(float);
    const int use_hist = (ws_size >= need_hist) ? 1 : 0;

    // zero h0/h1 slots and c0/c1 (re-runs inside the graph on every replay)
    hipMemsetAsync(d_ws, 0, (size_t)6 * BH * sizeof(float), stream);

    const int nblk = use_hist ? 256 : 272;
    const int kmax = use_hist ? S : (S + 1);   // inclusive
    for (int k = 0; k <= kmax; ++k) {
        lstm_phase<<<nblk, 256, 0, stream>>>(x, Wx0, bx0, Wh0, bh0,
                                             Wx1, bx1, Wh1, bh1, Wfc, bfc,
                                             out, ws, k, use_hist);
    }
    if (use_hist) {
        dim3 g(B * S / 64, DOUT / 64);
        fc_kernel<<<g, 256, 0, stream>>>(ws + 6 * BH, Wfc, bfc, out);
    }
}

// Round 2
// 100298.053 us; speedup vs baseline: 3.4211x; 3.4211x over previous
//
#include <hip/hip_runtime.h>
#include <math.h>

#define B    32
#define S    2048
#define DIN  256
#define H    512
#define G    2048   // 4H
#define DOUT 256
#define BH   (B*H)
#define CPAD 260    // LDS chunk leading dim (floats), breaks bank conflicts

// ws layout (float offsets)
#define OFF_H0   0
#define OFF_H1   (2*BH)
#define OFF_C0   (4*BH)
#define OFF_C1   (5*BH)
#define OFF_B0   (6*BH)
#define OFF_B1   (6*BH + G)
#define OFF_W0X  (6*BH + 2*G)
#define OFF_W0H  (OFF_W0X + DIN*G)
#define OFF_W1X  (OFF_W0H + H*G)
#define OFF_W1H  (OFF_W1X + H*G)
#define OFF_HIST (OFF_W1H + H*G)     // 3,772,416 floats

__device__ __forceinline__ float sigf(float v) { return 1.0f / (1.0f + expf(-v)); }

// packed col p -> original gate col: block bb owns 4 hidden units, 4 gates each
__device__ __forceinline__ int origcol(int p) {
    return ((p >> 2) & 3) * H + (p >> 4) * 4 + (p & 3);
}

// One-time: repack weights block-major + combine biases into ws.
__global__ __launch_bounds__(256) void repack(
    const float* __restrict__ Wx0, const float* __restrict__ bx0,
    const float* __restrict__ Wh0, const float* __restrict__ bh0,
    const float* __restrict__ Wx1, const float* __restrict__ bx1,
    const float* __restrict__ Wh1, const float* __restrict__ bh1,
    float* __restrict__ ws)
{
    const int total = (DIN + 3 * H) * G;                 // 3,670,016
    const int idx = blockIdx.x * 256 + threadIdx.x;
    if (idx < total) {
        const int p = idx & (G - 1);
        const int krow = idx >> 11;
        const int oc = origcol(p);
        float v;
        if      (krow < DIN)         v = Wx0[(size_t)krow * G + oc];
        else if (krow < DIN + H)     v = Wh0[(size_t)(krow - DIN) * G + oc];
        else if (krow < DIN + 2*H)   v = Wx1[(size_t)(krow - DIN - H) * G + oc];
        else                         v = Wh1[(size_t)(krow - DIN - 2*H) * G + oc];
        ws[OFF_W0X + idx] = v;
    } else {
        const int q = idx - total;
        if (q < G)          ws[OFF_B0 + q]     = bx0[origcol(q)] + bh0[origcol(q)];
        else if (q < 2*G)   ws[OFF_B1 + q - G] = bx1[origcol(q - G)] + bh1[origcol(q - G)];
    }
}

// Phase k: blocks [0,128)=layer0 t=k, [128,256)=layer1 t=k-1,
//          [256,272)=fallback FC t=k-2 (only when !use_hist)
__global__ __launch_bounds__(512) void lstm_phase(
    const float* __restrict__ x,
    const float* __restrict__ Wx0, const float* __restrict__ bx0,
    const float* __restrict__ Wh0, const float* __restrict__ bh0,
    const float* __restrict__ Wx1, const float* __restrict__ bx1,
    const float* __restrict__ Wh1, const float* __restrict__ bh1,
    const float* __restrict__ Wfc, const float* __restrict__ bfc,
    float* __restrict__ out, float* __restrict__ ws,
    int k, int use_hist, int packed)
{
    __shared__ float Alds[32 * CPAD];        // 33.3 KB staging chunk [32][260]
    __shared__ float Pt[4 * 32 * 16];        // 8 KB K-split partials / gate exchange

    float* h0s  = ws + OFF_H0;
    float* h1s  = ws + OFF_H1;
    float* c0s  = ws + OFF_C0;
    float* c1s  = ws + OFF_C1;
    float* hist = ws + OFF_HIST;

    const int blk = blockIdx.x;
    const int tid = threadIdx.x;
    const int cg  = tid & 3;                 // gate (or colgroup)
    const int r   = (tid >> 2) & 31;         // batch row
    const int kq  = tid >> 7;                // K quarter

    int role, t;
    if      (blk < 128) { role = 0; t = k; }
    else if (blk < 256) { role = 1; t = k - 1; }
    else                { role = 2; t = k - 2; }
    if (t < 0 || t >= S) return;

    const int b = (role == 0) ? blk : (role == 1 ? blk - 128 : blk - 256);
    const int hb = b * 4;

    // per-chunk descriptors
    const float* asrc[4]; long ars[4];
    const float* wsrc[4];
    int nchunk; long wstride;
    const int par_t  = t & 1;
    const int par_tm = (t + 1) & 1;          // (t-1)&1

    if (role == 0) {
        nchunk = 3; wstride = G;
        asrc[0] = x + (size_t)t * DIN;              ars[0] = (long)S * DIN;
        asrc[1] = h0s + par_tm * BH;                ars[1] = H;
        asrc[2] = h0s + par_tm * BH + 256;          ars[2] = H;
        if (packed) {
            wsrc[0] = ws + OFF_W0X;
            wsrc[1] = ws + OFF_W0H;
            wsrc[2] = ws + OFF_W0H + (size_t)256 * G;
        } else {
            wsrc[0] = Wx0; wsrc[1] = Wh0; wsrc[2] = Wh0 + (size_t)256 * G;
        }
    } else if (role == 1) {
        nchunk = 4; wstride = G;
        asrc[0] = h0s + par_t * BH;                 ars[0] = H;
        asrc[1] = h0s + par_t * BH + 256;           ars[1] = H;
        asrc[2] = h1s + par_tm * BH;                ars[2] = H;
        asrc[3] = h1s + par_tm * BH + 256;          ars[3] = H;
        if (packed) {
            wsrc[0] = ws + OFF_W1X;
            wsrc[1] = ws + OFF_W1X + (size_t)256 * G;
            wsrc[2] = ws + OFF_W1H;
            wsrc[3] = ws + OFF_W1H + (size_t)256 * G;
        } else {
            wsrc[0] = Wx1; wsrc[1] = Wx1 + (size_t)256 * G;
            wsrc[2] = Wh1; wsrc[3] = Wh1 + (size_t)256 * G;
        }
    } else {
        nchunk = 2; wstride = DOUT;
        asrc[0] = h1s + par_t * BH;                 ars[0] = H;
        asrc[1] = h1s + par_t * BH + 256;           ars[1] = H;
        wsrc[0] = Wfc; wsrc[1] = Wfc + (size_t)256 * DOUT;
    }

    // weight column base for this thread's 4 columns
    int wcol;
    if (role == 2)        wcol = b * 16 + cg * 4;
    else if (packed)      wcol = b * 16 + cg * 4;      // packed col space
    else                  wcol = cg * H + hb;          // original col space

    float4 acc = {0.f, 0.f, 0.f, 0.f};

    for (int ch = 0; ch < nchunk; ++ch) {
        // stage A chunk [32][256] -> Alds[32][260]
        const float4* s4 = (const float4*)asrc[ch];
        const long rs4 = ars[ch] >> 2;
        float4* d4 = (float4*)Alds;
        #pragma unroll
        for (int i = tid; i < 32 * 64; i += 512) {
            const int rr = i >> 6, k4 = i & 63;
            d4[rr * (CPAD / 4) + k4] = s4[rr * rs4 + k4];
        }
        __syncthreads();

        const float* wp = wsrc[ch] + (size_t)(kq * 64) * wstride + wcol;
        const float* ap = Alds + r * CPAD + kq * 64;
        #pragma unroll 16
        for (int kk = 0; kk < 64; ++kk) {
            const float4 w = *(const float4*)(wp + (size_t)kk * wstride);
            const float a = ap[kk];
            acc.x = fmaf(a, w.x, acc.x);
            acc.y = fmaf(a, w.y, acc.y);
            acc.z = fmaf(a, w.z, acc.z);
            acc.w = fmaf(a, w.w, acc.w);
        }
        __syncthreads();
    }

    // K-split partials -> LDS
    {
        float* pp = Pt + (kq * 32 + r) * 16 + cg * 4;
        pp[0] = acc.x; pp[1] = acc.y; pp[2] = acc.z; pp[3] = acc.w;
    }
    __syncthreads();

    // reduce 4 partials; thread (rr, c)
    const int rr = tid >> 4, c = tid & 15;
    float gval = Pt[(0 * 32 + rr) * 16 + c] + Pt[(1 * 32 + rr) * 16 + c]
               + Pt[(2 * 32 + rr) * 16 + c] + Pt[(3 * 32 + rr) * 16 + c];

    if (role == 2) {
        const int col = b * 16 + c;
        out[((size_t)rr * S + t) * DOUT + col] = gval + bfc[col];
        return;
    }

    // bias
    float bias;
    if (packed) bias = ws[(role ? OFF_B1 : OFF_B0) + b * 16 + c];
    else {
        const int oc = (c >> 2) * H + hb + (c & 3);
        bias = role ? (bx1[oc] + bh1[oc]) : (bx0[oc] + bh0[oc]);
    }
    Pt[rr * 16 + c] = gval + bias;     // each thread overwrites only what it read
    __syncthreads();

    if (tid < 128) {
        const int r2 = tid >> 2, sub = tid & 3;
        const float f  = Pt[r2 * 16 + 0  + sub];
        const float i  = Pt[r2 * 16 + 4  + sub];
        const float g  = Pt[r2 * 16 + 8  + sub];
        const float o  = Pt[r2 * 16 + 12 + sub];
        const int j = hb + sub;
        float* cst = (role ? c1s : c0s) + r2 * H + j;
        const float cn = sigf(f) * (*cst) + sigf(i) * tanhf(g);
        const float hn = sigf(o) * tanhf(cn);
        *cst = cn;
        (role ? h1s : h0s)[par_t * BH + r2 * H + j] = hn;
        if (role == 1 && use_hist) hist[((size_t)r2 * S + t) * H + j] = hn;
    }
}

// Final projection: out[B*S, DOUT] = hist[B*S, H] @ Wfc[H, DOUT] + bfc
__global__ __launch_bounds__(256) void fc_kernel(
    const float* __restrict__ A, const float* __restrict__ Wfc,
    const float* __restrict__ bfc, float* __restrict__ out)
{
    __shared__ float As[64][65];
    __shared__ float Wsh[64][65];
    const int rb  = blockIdx.x * 64;
    const int cb  = blockIdx.y * 64;
    const int tid = threadIdx.x;
    const int tr  = tid >> 4, tc = tid & 15;
    float acc[4][4] = {};
    for (int k0 = 0; k0 < H; k0 += 64) {
        for (int idx = tid; idx < 64 * 64; idx += 256) {
            const int r = idx >> 6, kk = idx & 63;
            As[r][kk]  = A[(size_t)(rb + r) * H + k0 + kk];
            Wsh[r][kk] = Wfc[(size_t)(k0 + r) * DOUT + cb + kk];
        }
        __syncthreads();
        #pragma unroll 16
        for (int kk = 0; kk < 64; ++kk) {
            float av[4], wv[4];
            #pragma unroll
            for (int i = 0; i < 4; ++i) av[i] = As[tr * 4 + i][kk];
            #pragma unroll
            for (int j = 0; j < 4; ++j) wv[j] = Wsh[kk][tc * 4 + j];
            #pragma unroll
            for (int i = 0; i < 4; ++i)
                #pragma unroll
                for (int j = 0; j < 4; ++j)
                    acc[i][j] = fmaf(av[i], wv[j], acc[i][j]);
        }
        __syncthreads();
    }
    #pragma unroll
    for (int i = 0; i < 4; ++i) {
        const size_t rw = rb + tr * 4 + i;
        #pragma unroll
        for (int j = 0; j < 4; ++j) {
            const int cc = cb + tc * 4 + j;
            out[rw * DOUT + cc] = acc[i][j] + bfc[cc];
        }
    }
}

extern "C" void kernel_launch(void* const* d_in, const int* in_sizes, int n_in,
                              void* d_out, int out_size, void* d_ws, size_t ws_size,
                              hipStream_t stream)
{
    const float* x   = (const float*)d_in[0];
    const float* Wx0 = (const float*)d_in[1];
    const float* bx0 = (const float*)d_in[2];
    const float* Wh0 = (const float*)d_in[3];
    const float* bh0 = (const float*)d_in[4];
    const float* Wx1 = (const float*)d_in[5];
    const float* bx1 = (const float*)d_in[6];
    const float* Wh1 = (const float*)d_in[7];
    const float* bh1 = (const float*)d_in[8];
    const float* Wfc = (const float*)d_in[9];
    const float* bfc = (const float*)d_in[10];
    float* out = (float*)d_out;
    float* ws  = (float*)d_ws;

    const size_t need_pack = (size_t)OFF_HIST * sizeof(float);
    const size_t need_hist = need_pack + (size_t)B * S * H * sizeof(float);
    const int packed   = (ws_size >= need_pack) ? 1 : 0;
    const int use_hist = (ws_size >= need_hist) ? 1 : 0;

    hipMemsetAsync(d_ws, 0, (size_t)6 * BH * sizeof(float), stream);
    if (packed) {
        const int total = (DIN + 3 * H) * G + 2 * G;
        repack<<<(total + 255) / 256, 256, 0, stream>>>(Wx0, bx0, Wh0, bh0,
                                                        Wx1, bx1, Wh1, bh1, ws);
    }

    const int nblk = use_hist ? 256 : 272;
    const int kmax = use_hist ? S : (S + 1);   // inclusive
    for (int k = 0; k <= kmax; ++k) {
        lstm_phase<<<nblk, 512, 0, stream>>>(x, Wx0, bx0, Wh0, bh0,
                                             Wx1, bx1, Wh1, bh1, Wfc, bfc,
                                             out, ws, k, use_hist, packed);
    }
    if (use_hist) {
        dim3 g(B * S / 64, DOUT / 64);
        fc_kernel<<<g, 256, 0, stream>>>(ws + OFF_HIST, Wfc, bfc, out);
    }
}

// Round 3
// 31743.500 us; speedup vs baseline: 10.8096x; 3.1596x over previous
//
#include <hip/hip_runtime.h>
#include <math.h>

#define B    32
#define S    2048
#define DIN  256
#define H    512
#define G    2048   // 4H
#define DOUT 256
#define BH   (B*H)
#define CPAD 260    // LDS A-chunk leading dim (floats): stride-260 => 2-way max conflict

// ws layout (float offsets)
#define OFF_H0   0
#define OFF_H1   (2*BH)
#define OFF_C0   (4*BH)
#define OFF_C1   (5*BH)
#define OFF_B0   (6*BH)
#define OFF_B1   (6*BH + G)
#define OFF_W0X  (6*BH + 2*G)
#define OFF_W0H  (OFF_W0X + DIN*G)
#define OFF_W1X  (OFF_W0H + H*G)
#define OFF_W1H  (OFF_W1X + H*G)
#define OFF_HIST (OFF_W1H + H*G)     // 3,772,416 floats

__device__ __forceinline__ float sigf(float v) { return 1.0f / (1.0f + expf(-v)); }

// packed col p -> original gate col: block bb owns 4 hidden units x 4 gates (16 contiguous)
__device__ __forceinline__ int origcol(int p) {
    return ((p >> 2) & 3) * H + (p >> 4) * 4 + (p & 3);
}

// One-time: repack weights block-major + combine biases into ws.
__global__ __launch_bounds__(256) void repack(
    const float* __restrict__ Wx0, const float* __restrict__ bx0,
    const float* __restrict__ Wh0, const float* __restrict__ bh0,
    const float* __restrict__ Wx1, const float* __restrict__ bx1,
    const float* __restrict__ Wh1, const float* __restrict__ bh1,
    float* __restrict__ ws)
{
    const int total = (DIN + 3 * H) * G;                 // 3,670,016
    const int idx = blockIdx.x * 256 + threadIdx.x;
    if (idx < total) {
        const int p = idx & (G - 1);
        const int krow = idx >> 11;
        const int oc = origcol(p);
        float v;
        if      (krow < DIN)         v = Wx0[(size_t)krow * G + oc];
        else if (krow < DIN + H)     v = Wh0[(size_t)(krow - DIN) * G + oc];
        else if (krow < DIN + 2*H)   v = Wx1[(size_t)(krow - DIN - H) * G + oc];
        else                         v = Wh1[(size_t)(krow - DIN - 2*H) * G + oc];
        ws[OFF_W0X + idx] = v;
    } else {
        const int q = idx - total;
        if (q < G)          ws[OFF_B0 + q]     = bx0[origcol(q)] + bh0[origcol(q)];
        else if (q < 2*G)   ws[OFF_B1 + q - G] = bx1[origcol(q - G)] + bh1[origcol(q - G)];
    }
}

// Phase k: blocks [0,128)=layer0 t=k, [128,256)=layer1 t=k-1,
//          [256,272)=fallback FC t=k-2 (only when !use_hist)
__global__ __launch_bounds__(512) void lstm_phase(
    const float* __restrict__ x,
    const float* __restrict__ Wx0, const float* __restrict__ bx0,
    const float* __restrict__ Wh0, const float* __restrict__ bh0,
    const float* __restrict__ Wx1, const float* __restrict__ bx1,
    const float* __restrict__ Wh1, const float* __restrict__ bh1,
    const float* __restrict__ Wfc, const float* __restrict__ bfc,
    float* __restrict__ out, float* __restrict__ ws,
    int k, int use_hist, int packed)
{
    __shared__ float Alds[32 * CPAD];        // 33.3 KB  A chunk [32][256] (+pad)
    __shared__ float Wlds[256 * 16];         // 16 KB    W chunk [256 k][16 cols]
    __shared__ float Pt[4 * 32 * 16];        // 8 KB     K-split partials / gate exchange

    float* h0s  = ws + OFF_H0;
    float* h1s  = ws + OFF_H1;
    float* c0s  = ws + OFF_C0;
    float* c1s  = ws + OFF_C1;
    float* hist = ws + OFF_HIST;

    const int blk = blockIdx.x;
    const int tid = threadIdx.x;
    const int cg  = tid & 3;                 // col group (4 cols each)
    const int r   = (tid >> 2) & 31;         // batch row
    const int kq  = tid >> 7;                // K quarter (64 k each)

    int role, t;
    if      (blk < 128) { role = 0; t = k; }
    else if (blk < 256) { role = 1; t = k - 1; }
    else                { role = 2; t = k - 2; }
    if (t < 0 || t >= S) return;

    const int b  = (role == 0) ? blk : (role == 1 ? blk - 128 : blk - 256);
    const int hb = b * 4;

    const float* asrc[4]; long ars[4];
    const float* wsrc[4];
    int nchunk; long wstride;
    const int par_t  = t & 1;
    const int par_tm = (t + 1) & 1;          // (t-1)&1

    if (role == 0) {
        nchunk = 3; wstride = G;
        asrc[0] = x + (size_t)t * DIN;              ars[0] = (long)S * DIN;
        asrc[1] = h0s + par_tm * BH;                ars[1] = H;
        asrc[2] = h0s + par_tm * BH + 256;          ars[2] = H;
        if (packed) {
            wsrc[0] = ws + OFF_W0X;
            wsrc[1] = ws + OFF_W0H;
            wsrc[2] = ws + OFF_W0H + (size_t)256 * G;
        } else {
            wsrc[0] = Wx0; wsrc[1] = Wh0; wsrc[2] = Wh0 + (size_t)256 * G;
        }
    } else if (role == 1) {
        nchunk = 4; wstride = G;
        asrc[0] = h0s + par_t * BH;                 ars[0] = H;
        asrc[1] = h0s + par_t * BH + 256;           ars[1] = H;
        asrc[2] = h1s + par_tm * BH;                ars[2] = H;
        asrc[3] = h1s + par_tm * BH + 256;          ars[3] = H;
        if (packed) {
            wsrc[0] = ws + OFF_W1X;
            wsrc[1] = ws + OFF_W1X + (size_t)256 * G;
            wsrc[2] = ws + OFF_W1H;
            wsrc[3] = ws + OFF_W1H + (size_t)256 * G;
        } else {
            wsrc[0] = Wx1; wsrc[1] = Wx1 + (size_t)256 * G;
            wsrc[2] = Wh1; wsrc[3] = Wh1 + (size_t)256 * G;
        }
    } else {
        nchunk = 2; wstride = DOUT;
        asrc[0] = h1s + par_t * BH;                 ars[0] = H;
        asrc[1] = h1s + par_t * BH + 256;           ars[1] = H;
        wsrc[0] = Wfc; wsrc[1] = Wfc + (size_t)256 * DOUT;
    }

    // W staging column mapping: float4 slot q (0..3) -> column offset
    int wq_base, wq_mul;
    if (role == 2 || packed) { wq_base = b * 16; wq_mul = 4; }   // 16 contiguous cols
    else                     { wq_base = hb;     wq_mul = H; }   // 4 gates at H apart

    float4 acc = {0.f, 0.f, 0.f, 0.f};

    for (int ch = 0; ch < nchunk; ++ch) {
        // ---- stage A chunk [32][256] -> Alds (float4, coalesced) ----
        const float4* s4 = (const float4*)asrc[ch];
        const long rs4 = ars[ch] >> 2;
        #pragma unroll
        for (int j = 0; j < 4; ++j) {
            const int i  = tid + j * 512;
            const int rr = i >> 6, k4 = i & 63;
            *(float4*)&Alds[rr * CPAD + k4 * 4] = s4[rr * rs4 + k4];
        }
        // ---- stage W chunk [256][16] -> Wlds ----
        const float* wsc = wsrc[ch];
        #pragma unroll
        for (int j = 0; j < 2; ++j) {
            const int s2  = tid + j * 512;
            const int row = s2 >> 2, q = s2 & 3;
            *(float4*)&Wlds[row * 16 + q * 4] =
                *(const float4*)(wsc + (size_t)row * wstride + wq_base + q * wq_mul);
        }
        __syncthreads();

        // ---- LDS-only inner product: 4 cols x 64 k per thread ----
        const float* ap = Alds + r * CPAD + kq * 64;
        const float* wp = Wlds + kq * (64 * 16) + cg * 4;
        #pragma unroll
        for (int kk = 0; kk < 64; kk += 4) {
            const float4 a4 = *(const float4*)(ap + kk);
            const float4 w0 = *(const float4*)(wp + (kk + 0) * 16);
            const float4 w1 = *(const float4*)(wp + (kk + 1) * 16);
            const float4 w2 = *(const float4*)(wp + (kk + 2) * 16);
            const float4 w3 = *(const float4*)(wp + (kk + 3) * 16);
            acc.x = fmaf(a4.x, w0.x, acc.x); acc.y = fmaf(a4.x, w0.y, acc.y);
            acc.z = fmaf(a4.x, w0.z, acc.z); acc.w = fmaf(a4.x, w0.w, acc.w);
            acc.x = fmaf(a4.y, w1.x, acc.x); acc.y = fmaf(a4.y, w1.y, acc.y);
            acc.z = fmaf(a4.y, w1.z, acc.z); acc.w = fmaf(a4.y, w1.w, acc.w);
            acc.x = fmaf(a4.z, w2.x, acc.x); acc.y = fmaf(a4.z, w2.y, acc.y);
            acc.z = fmaf(a4.z, w2.z, acc.z); acc.w = fmaf(a4.z, w2.w, acc.w);
            acc.x = fmaf(a4.w, w3.x, acc.x); acc.y = fmaf(a4.w, w3.y, acc.y);
            acc.z = fmaf(a4.w, w3.z, acc.z); acc.w = fmaf(a4.w, w3.w, acc.w);
        }
        __syncthreads();
    }

    // ---- K-split partials -> LDS ----
    {
        float* pp = Pt + (kq * 32 + r) * 16 + cg * 4;
        pp[0] = acc.x; pp[1] = acc.y; pp[2] = acc.z; pp[3] = acc.w;
    }
    __syncthreads();

    // ---- reduce 4 partials; thread (rr, c) ----
    const int rr = tid >> 4, c = tid & 15;
    float gval = Pt[(0 * 32 + rr) * 16 + c] + Pt[(1 * 32 + rr) * 16 + c]
               + Pt[(2 * 32 + rr) * 16 + c] + Pt[(3 * 32 + rr) * 16 + c];

    if (role == 2) {
        const int col = b * 16 + c;
        out[((size_t)rr * S + t) * DOUT + col] = gval + bfc[col];
        return;
    }

    float bias;
    if (packed) bias = ws[(role ? OFF_B1 : OFF_B0) + b * 16 + c];
    else {
        const int oc = (c >> 2) * H + hb + (c & 3);
        bias = role ? (bx1[oc] + bh1[oc]) : (bx0[oc] + bh0[oc]);
    }
    Pt[rr * 16 + c] = gval + bias;
    __syncthreads();

    if (tid < 128) {
        const int r2 = tid >> 2, sub = tid & 3;
        const float f  = Pt[r2 * 16 + 0  + sub];
        const float i  = Pt[r2 * 16 + 4  + sub];
        const float g  = Pt[r2 * 16 + 8  + sub];
        const float o  = Pt[r2 * 16 + 12 + sub];
        const int j = hb + sub;
        float* cst = (role ? c1s : c0s) + r2 * H + j;
        const float cn = sigf(f) * (*cst) + sigf(i) * tanhf(g);
        const float hn = sigf(o) * tanhf(cn);
        *cst = cn;
        (role ? h1s : h0s)[par_t * BH + r2 * H + j] = hn;
        if (role == 1 && use_hist) hist[((size_t)r2 * S + t) * H + j] = hn;
    }
}

// Final projection: out[B*S, DOUT] = hist[B*S, H] @ Wfc[H, DOUT] + bfc
__global__ __launch_bounds__(256) void fc_kernel(
    const float* __restrict__ A, const float* __restrict__ Wfc,
    const float* __restrict__ bfc, float* __restrict__ out)
{
    __shared__ float As[64][65];
    __shared__ float Wsh[64][65];
    const int rb  = blockIdx.x * 64;
    const int cb  = blockIdx.y * 64;
    const int tid = threadIdx.x;
    const int tr  = tid >> 4, tc = tid & 15;
    float acc[4][4] = {};
    for (int k0 = 0; k0 < H; k0 += 64) {
        for (int idx = tid; idx < 64 * 64; idx += 256) {
            const int r = idx >> 6, kk = idx & 63;
            As[r][kk]  = A[(size_t)(rb + r) * H + k0 + kk];
            Wsh[r][kk] = Wfc[(size_t)(k0 + r) * DOUT + cb + kk];
        }
        __syncthreads();
        #pragma unroll 16
        for (int kk = 0; kk < 64; ++kk) {
            float av[4], wv[4];
            #pragma unroll
            for (int i = 0; i < 4; ++i) av[i] = As[tr * 4 + i][kk];
            #pragma unroll
            for (int j = 0; j < 4; ++j) wv[j] = Wsh[kk][tc * 4 + j];
            #pragma unroll
            for (int i = 0; i < 4; ++i)
                #pragma unroll
                for (int j = 0; j < 4; ++j)
                    acc[i][j] = fmaf(av[i], wv[j], acc[i][j]);
        }
        __syncthreads();
    }
    #pragma unroll
    for (int i = 0; i < 4; ++i) {
        const size_t rw = rb + tr * 4 + i;
        #pragma unroll
        for (int j = 0; j < 4; ++j) {
            const int cc = cb + tc * 4 + j;
            out[rw * DOUT + cc] = acc[i][j] + bfc[cc];
        }
    }
}

extern "C" void kernel_launch(void* const* d_in, const int* in_sizes, int n_in,
                              void* d_out, int out_size, void* d_ws, size_t ws_size,
                              hipStream_t stream)
{
    const float* x   = (const float*)d_in[0];
    const float* Wx0 = (const float*)d_in[1];
    const float* bx0 = (const float*)d_in[2];
    const float* Wh0 = (const float*)d_in[3];
    const float* bh0 = (const float*)d_in[4];
    const float* Wx1 = (const float*)d_in[5];
    const float* bx1 = (const float*)d_in[6];
    const float* Wh1 = (const float*)d_in[7];
    const float* bh1 = (const float*)d_in[8];
    const float* Wfc = (const float*)d_in[9];
    const float* bfc = (const float*)d_in[10];
    float* out = (float*)d_out;
    float* ws  = (float*)d_ws;

    const size_t need_pack = (size_t)OFF_HIST * sizeof(float);
    const size_t need_hist = need_pack + (size_t)B * S * H * sizeof(float);
    const int packed   = (ws_size >= need_pack) ? 1 : 0;
    const int use_hist = (ws_size >= need_hist) ? 1 : 0;

    hipMemsetAsync(d_ws, 0, (size_t)6 * BH * sizeof(float), stream);
    if (packed) {
        const int total = (DIN + 3 * H) * G + 2 * G;
        repack<<<(total + 255) / 256, 256, 0, stream>>>(Wx0, bx0, Wh0, bh0,
                                                        Wx1, bx1, Wh1, bh1, ws);
    }

    const int nblk = use_hist ? 256 : 272;
    const int kmax = use_hist ? S : (S + 1);   // inclusive
    for (int k = 0; k <= kmax; ++k) {
        lstm_phase<<<nblk, 512, 0, stream>>>(x, Wx0, bx0, Wh0, bh0,
                                             Wx1, bx1, Wh1, bh1, Wfc, bfc,
                                             out, ws, k, use_hist, packed);
    }
    if (use_hist) {
        dim3 g(B * S / 64, DOUT / 64);
        fc_kernel<<<g, 256, 0, stream>>>(ws + OFF_HIST, Wfc, bfc, out);
    }
}

// Round 4
// 18558.505 us; speedup vs baseline: 18.4893x; 1.7105x over previous
//
#include <hip/hip_runtime.h>
#include <math.h>

#define B    32
#define S    2048
#define DIN  256
#define H    512
#define G    2048   // 4H
#define DOUT 256

typedef __attribute__((ext_vector_type(8))) short bf16x8;
typedef __attribute__((ext_vector_type(4))) float f32x4;

#define MFMA(a, b, c) __builtin_amdgcn_mfma_f32_16x16x32_bf16((a), (b), (c), 0, 0, 0)

// ---- ws byte offsets ----
#define OB_C0        0u          // fp32 [32][512]
#define OB_C1        65536u
#define OB_H0HI      131072u     // bf16 [2][32][512]
#define OB_H0LO      196608u
#define OB_H1HI      262144u
#define OB_H1LO      327680u
#define OB_H1F32     393216u     // fp32 [2][32][512] (fallback FC)
#define OB_STATE_END 524288u
#define OB_B0        524288u     // fp32 [2048] combined bias, packed cols
#define OB_B1        532480u
#define OB_FHI       540672u     // bf16 [256][512]  Wfc^T split
#define OB_FLO       802816u
#define OB_W0HI      1064960u    // bf16 [2048][768]  [Wx0;Wh0]^T packed-col split
#define OB_W0LO      4210688u
#define OB_W1HI      7356416u    // bf16 [2048][1024] [Wx1;Wh1]^T packed-col split
#define OB_W1LO      11550720u
#define OB_CORE_END  15745024u
#define OB_HISTHI    15745024u   // bf16 [B*S][512] h1 history split
#define OB_HISTLO    82853888u
#define OB_HIST_END  149962752u
#define OB_XHI       149962752u  // bf16 [B][S][256] x split
#define OB_XLO       183517184u
#define OB_FULL_END  217071616u

__device__ __forceinline__ float sigf(float v) { return 1.0f / (1.0f + expf(-v)); }

__device__ __forceinline__ unsigned short f2b(float f) {   // fp32 -> bf16 RNE
    union { float f; unsigned u; } v; v.f = f;
    unsigned r = v.u + 0x7fffu + ((v.u >> 16) & 1u);
    return (unsigned short)(r >> 16);
}
__device__ __forceinline__ float b2f(unsigned short h) {
    union { unsigned u; float f; } v; v.u = ((unsigned)h) << 16; return v.f;
}
__device__ __forceinline__ void split8(const float* __restrict__ p, bf16x8& hi, bf16x8& lo) {
    #pragma unroll
    for (int j = 0; j < 8; ++j) {
        const float v = p[j];
        const unsigned short h = f2b(v);
        hi[j] = (short)h;
        lo[j] = (short)f2b(v - b2f(h));
    }
}

// ---- repack: W -> column-major packed split bf16 ----
__global__ __launch_bounds__(256) void repack_w(
    const float* __restrict__ s1, const float* __restrict__ s2,
    int k1, int K, int srcld, int dopack,
    unsigned short* __restrict__ hi, unsigned short* __restrict__ lo)
{
    const int p  = blockIdx.x;
    const int kk = blockIdx.y * 256 + threadIdx.x;
    if (kk >= K) return;
    const int oc = dopack ? ((((p >> 2) & 3) * H) + ((p >> 4) << 2) + (p & 3)) : p;
    const float w = (kk < k1) ? s1[(size_t)kk * srcld + oc]
                              : s2[(size_t)(kk - k1) * srcld + oc];
    const unsigned short h = f2b(w);
    hi[(size_t)p * K + kk] = h;
    lo[(size_t)p * K + kk] = f2b(w - b2f(h));
}

__global__ __launch_bounds__(256) void repack_bias(
    const float* __restrict__ bx0, const float* __restrict__ bh0,
    const float* __restrict__ bx1, const float* __restrict__ bh1,
    float* __restrict__ wsf)
{
    const int q = blockIdx.x * 256 + threadIdx.x;
    if (q >= 2 * G) return;
    const int p  = q & (G - 1);
    const int oc = (((p >> 2) & 3) * H) + ((p >> 4) << 2) + (p & 3);
    float* dst = (float*)((char*)wsf + (q < G ? OB_B0 : OB_B1));
    dst[p] = (q < G) ? (bx0[oc] + bh0[oc]) : (bx1[oc] + bh1[oc]);
}

__global__ __launch_bounds__(256) void repack_x(const float* __restrict__ x, float* __restrict__ wsf)
{
    unsigned short* xhi = (unsigned short*)((char*)wsf + OB_XHI);
    unsigned short* xlo = (unsigned short*)((char*)wsf + OB_XLO);
    const size_t n = (size_t)B * S * DIN;
    for (size_t i = (size_t)blockIdx.x * 256 + threadIdx.x; i < n; i += (size_t)gridDim.x * 256) {
        const float v = x[i];
        const unsigned short h = f2b(v);
        xhi[i] = h;
        xlo[i] = f2b(v - b2f(h));
    }
}

// ---- fragment loads for one kslice ----
__device__ __forceinline__ void load_frags(
    bool L1, int xsplit, int ks, int lane, int p0,
    const unsigned short* __restrict__ WHI, const unsigned short* __restrict__ WLO, int K,
    const unsigned short* __restrict__ h0hi, const unsigned short* __restrict__ h0lo,
    const unsigned short* __restrict__ h1hi, const unsigned short* __restrict__ h1lo,
    const unsigned short* __restrict__ xhi,  const unsigned short* __restrict__ xlo,
    const float* __restrict__ xf, int t,
    bf16x8& bh, bf16x8& bl, bf16x8& a0h, bf16x8& a0l, bf16x8& a1h, bf16x8& a1l)
{
    const int kf = ks * 32 + ((lane >> 4) << 3);
    const size_t wo = (size_t)(p0 + (lane & 15)) * K + kf;
    bh = *(const bf16x8*)(WHI + wo);
    bl = *(const bf16x8*)(WLO + wo);
    const int r0 = lane & 15, r1 = r0 + 16;
    if (L1) {
        const unsigned short* shi = (kf < 512) ? h0hi : h1hi;
        const unsigned short* slo = (kf < 512) ? h0lo : h1lo;
        const int kk = kf & 511;
        a0h = *(const bf16x8*)(shi + r0 * 512 + kk);
        a0l = *(const bf16x8*)(slo + r0 * 512 + kk);
        a1h = *(const bf16x8*)(shi + r1 * 512 + kk);
        a1l = *(const bf16x8*)(slo + r1 * 512 + kk);
    } else if (kf < 256) {
        if (xsplit) {
            const size_t o0 = ((size_t)r0 * S + t) * DIN + kf;
            const size_t o1 = ((size_t)r1 * S + t) * DIN + kf;
            a0h = *(const bf16x8*)(xhi + o0); a0l = *(const bf16x8*)(xlo + o0);
            a1h = *(const bf16x8*)(xhi + o1); a1l = *(const bf16x8*)(xlo + o1);
        } else {
            split8(xf + ((size_t)r0 * S + t) * DIN + kf, a0h, a0l);
            split8(xf + ((size_t)r1 * S + t) * DIN + kf, a1h, a1l);
        }
    } else {
        const int kk = kf - 256;
        a0h = *(const bf16x8*)(h0hi + r0 * 512 + kk);
        a0l = *(const bf16x8*)(h0lo + r0 * 512 + kk);
        a1h = *(const bf16x8*)(h0hi + r1 * 512 + kk);
        a1l = *(const bf16x8*)(h0lo + r1 * 512 + kk);
    }
}

// ---- one pipeline phase: blocks [0,128)=layer0 t=k, [128,256)=layer1 t=k-1 ----
__global__ __launch_bounds__(512) void lstm_phase(
    const float* __restrict__ x, float* __restrict__ wsf,
    int k, int xsplit, int hist)
{
    char* wsb = (char*)wsf;
    const int blk = blockIdx.x, tid = threadIdx.x;
    const int wave = tid >> 6, lane = tid & 63;
    const bool L1 = blk >= 128;
    const int t = L1 ? k - 1 : k;
    if (t < 0 || t >= S) return;
    const int b  = L1 ? blk - 128 : blk;
    const int K  = L1 ? 1024 : 768;
    const int ni = L1 ? 4 : 3;         // kslices per wave (8 waves k-split)
    const int par_t = t & 1, par_tm = (t + 1) & 1;

    const unsigned short* WHI = (const unsigned short*)(wsb + (L1 ? OB_W1HI : OB_W0HI));
    const unsigned short* WLO = (const unsigned short*)(wsb + (L1 ? OB_W1LO : OB_W0LO));
    const unsigned short* H0HI = (const unsigned short*)(wsb + OB_H0HI);
    const unsigned short* H0LO = (const unsigned short*)(wsb + OB_H0LO);
    const unsigned short* H1HI = (const unsigned short*)(wsb + OB_H1HI);
    const unsigned short* H1LO = (const unsigned short*)(wsb + OB_H1LO);
    const unsigned short* xhi  = (const unsigned short*)(wsb + OB_XHI);
    const unsigned short* xlo  = (const unsigned short*)(wsb + OB_XLO);

    const unsigned short *h0hi_r, *h0lo_r, *h1hi_r = 0, *h1lo_r = 0;
    if (L1) {
        h0hi_r = H0HI + par_t  * 16384; h0lo_r = H0LO + par_t  * 16384;
        h1hi_r = H1HI + par_tm * 16384; h1lo_r = H1LO + par_tm * 16384;
    } else {
        h0hi_r = H0HI + par_tm * 16384; h0lo_r = H0LO + par_tm * 16384;
    }

    const int p0 = b * 16;
    f32x4 acc0 = {0.f, 0.f, 0.f, 0.f}, acc1 = {0.f, 0.f, 0.f, 0.f};
    bf16x8 bh, bl, a0h, a0l, a1h, a1l;
    load_frags(L1, xsplit, wave, lane, p0, WHI, WLO, K,
               h0hi_r, h0lo_r, h1hi_r, h1lo_r, xhi, xlo, x, t,
               bh, bl, a0h, a0l, a1h, a1l);
    #pragma unroll
    for (int i = 0; i < 4; ++i) {
        if (i >= ni) break;
        bf16x8 nbh, nbl, n0h, n0l, n1h, n1l;
        if (i + 1 < ni)
            load_frags(L1, xsplit, wave + 8 * (i + 1), lane, p0, WHI, WLO, K,
                       h0hi_r, h0lo_r, h1hi_r, h1lo_r, xhi, xlo, x, t,
                       nbh, nbl, n0h, n0l, n1h, n1l);
        acc0 = MFMA(a0h, bh, acc0);
        acc1 = MFMA(a1h, bh, acc1);
        acc0 = MFMA(a0l, bh, acc0);
        acc1 = MFMA(a1l, bh, acc1);
        acc0 = MFMA(a0h, bl, acc0);
        acc1 = MFMA(a1h, bl, acc1);
        if (i + 1 < ni) { bh = nbh; bl = nbl; a0h = n0h; a0l = n0l; a1h = n1h; a1l = n1l; }
    }

    __shared__ float Pt[8][32][16];
    #pragma unroll
    for (int reg = 0; reg < 4; ++reg) {
        Pt[wave][((lane >> 4) << 2) + reg][lane & 15]      = acc0[reg];
        Pt[wave][16 + ((lane >> 4) << 2) + reg][lane & 15] = acc1[reg];
    }
    __syncthreads();

    const int row = tid >> 4, col = tid & 15;
    const float* Bp = (const float*)(wsb + (L1 ? OB_B1 : OB_B0));
    float g = Bp[p0 + col];
    #pragma unroll
    for (int w = 0; w < 8; ++w) g += Pt[w][row][col];
    Pt[0][row][col] = g;               // each thread reads/writes only its own slot
    __syncthreads();

    if (tid < 128) {
        const int r2 = tid >> 2, sub = tid & 3;
        const float fg = Pt[0][r2][0  + sub];
        const float ig = Pt[0][r2][4  + sub];
        const float gg = Pt[0][r2][8  + sub];
        const float og = Pt[0][r2][12 + sub];
        const int j = (b << 2) + sub;
        float* cst = (float*)(wsb + (L1 ? OB_C1 : OB_C0)) + r2 * H + j;
        const float cn = sigf(fg) * (*cst) + sigf(ig) * tanhf(gg);
        const float hn = sigf(og) * tanhf(cn);
        *cst = cn;
        const unsigned short hh = f2b(hn);
        const unsigned short hl = f2b(hn - b2f(hh));
        const int so = par_t * 16384 + r2 * H + j;
        if (!L1) {
            ((unsigned short*)(wsb + OB_H0HI))[so] = hh;
            ((unsigned short*)(wsb + OB_H0LO))[so] = hl;
        } else {
            ((unsigned short*)(wsb + OB_H1HI))[so] = hh;
            ((unsigned short*)(wsb + OB_H1LO))[so] = hl;
            ((float*)(wsb + OB_H1F32))[so] = hn;
            if (hist) {
                const size_t ho = ((size_t)r2 * S + t) * H + j;
                ((unsigned short*)(wsb + OB_HISTHI))[ho] = hh;
                ((unsigned short*)(wsb + OB_HISTLO))[ho] = hl;
            }
        }
    }
}

// ---- final FC from history (split MFMA): out[B*S,256] = hist @ Wfc + bfc ----
__global__ __launch_bounds__(256) void fc_split(
    const float* __restrict__ bfc, float* __restrict__ out, float* __restrict__ wsf)
{
    char* wsb = (char*)wsf;
    const unsigned short* AHI = (const unsigned short*)(wsb + OB_HISTHI);
    const unsigned short* ALO = (const unsigned short*)(wsb + OB_HISTLO);
    const unsigned short* FHI = (const unsigned short*)(wsb + OB_FHI);
    const unsigned short* FLO = (const unsigned short*)(wsb + OB_FLO);
    const int tid = threadIdx.x, wave = tid >> 6, lane = tid & 63;
    const size_t rb = (size_t)blockIdx.x * 32;
    const int colw = blockIdx.y * 64 + wave * 16 + (lane & 15);
    const size_t r0 = rb + (lane & 15), r1 = r0 + 16;
    f32x4 acc0 = {0.f, 0.f, 0.f, 0.f}, acc1 = {0.f, 0.f, 0.f, 0.f};
    for (int ks = 0; ks < 16; ++ks) {
        const int kf = ks * 32 + ((lane >> 4) << 3);
        const bf16x8 bh  = *(const bf16x8*)(FHI + (size_t)colw * 512 + kf);
        const bf16x8 bl  = *(const bf16x8*)(FLO + (size_t)colw * 512 + kf);
        const bf16x8 a0h = *(const bf16x8*)(AHI + r0 * 512 + kf);
        const bf16x8 a0l = *(const bf16x8*)(ALO + r0 * 512 + kf);
        const bf16x8 a1h = *(const bf16x8*)(AHI + r1 * 512 + kf);
        const bf16x8 a1l = *(const bf16x8*)(ALO + r1 * 512 + kf);
        acc0 = MFMA(a0h, bh, acc0);
        acc1 = MFMA(a1h, bh, acc1);
        acc0 = MFMA(a0l, bh, acc0);
        acc1 = MFMA(a1l, bh, acc1);
        acc0 = MFMA(a0h, bl, acc0);
        acc1 = MFMA(a1h, bl, acc1);
    }
    const float bias = bfc[colw];
    #pragma unroll
    for (int reg = 0; reg < 4; ++reg) {
        const size_t ro0 = rb + ((lane >> 4) << 2) + reg;
        out[ro0 * DOUT + colw]        = acc0[reg] + bias;
        out[(ro0 + 16) * DOUT + colw] = acc1[reg] + bias;
    }
}

// ---- fallback per-phase FC when ws can't hold history ----
__global__ __launch_bounds__(64) void fc_fallback(
    const float* __restrict__ bfc, float* __restrict__ out,
    float* __restrict__ wsf, int t)
{
    if (t < 0 || t >= S) return;
    char* wsb = (char*)wsf;
    const unsigned short* AHI = (const unsigned short*)(wsb + OB_H1HI) + (t & 1) * 16384;
    const unsigned short* ALO = (const unsigned short*)(wsb + OB_H1LO) + (t & 1) * 16384;
    const unsigned short* FHI = (const unsigned short*)(wsb + OB_FHI);
    const unsigned short* FLO = (const unsigned short*)(wsb + OB_FLO);
    const int lane = threadIdx.x;
    const int colw = blockIdx.x * 16 + (lane & 15);
    const int r0 = lane & 15, r1 = r0 + 16;
    f32x4 acc0 = {0.f, 0.f, 0.f, 0.f}, acc1 = {0.f, 0.f, 0.f, 0.f};
    for (int ks = 0; ks < 16; ++ks) {
        const int kf = ks * 32 + ((lane >> 4) << 3);
        const bf16x8 bh  = *(const bf16x8*)(FHI + (size_t)colw * 512 + kf);
        const bf16x8 bl  = *(const bf16x8*)(FLO + (size_t)colw * 512 + kf);
        const bf16x8 a0h = *(const bf16x8*)(AHI + r0 * 512 + kf);
        const bf16x8 a0l = *(const bf16x8*)(ALO + r0 * 512 + kf);
        const bf16x8 a1h = *(const bf16x8*)(AHI + r1 * 512 + kf);
        const bf16x8 a1l = *(const bf16x8*)(ALO + r1 * 512 + kf);
        acc0 = MFMA(a0h, bh, acc0);
        acc1 = MFMA(a1h, bh, acc1);
        acc0 = MFMA(a0l, bh, acc0);
        acc1 = MFMA(a1l, bh, acc1);
        acc0 = MFMA(a0h, bl, acc0);
        acc1 = MFMA(a1h, bl, acc1);
    }
    const float bias = bfc[colw];
    #pragma unroll
    for (int reg = 0; reg < 4; ++reg) {
        const int ro0 = ((lane >> 4) << 2) + reg;
        out[((size_t)ro0 * S + t) * DOUT + colw]        = acc0[reg] + bias;
        out[((size_t)(ro0 + 16) * S + t) * DOUT + colw] = acc1[reg] + bias;
    }
}

extern "C" void kernel_launch(void* const* d_in, const int* in_sizes, int n_in,
                              void* d_out, int out_size, void* d_ws, size_t ws_size,
                              hipStream_t stream)
{
    const float* x   = (const float*)d_in[0];
    const float* Wx0 = (const float*)d_in[1];
    const float* bx0 = (const float*)d_in[2];
    const float* Wh0 = (const float*)d_in[3];
    const float* bh0 = (const float*)d_in[4];
    const float* Wx1 = (const float*)d_in[5];
    const float* bx1 = (const float*)d_in[6];
    const float* Wh1 = (const float*)d_in[7];
    const float* bh1 = (const float*)d_in[8];
    const float* Wfc = (const float*)d_in[9];
    const float* bfc = (const float*)d_in[10];
    float* out = (float*)d_out;
    float* ws  = (float*)d_ws;
    char*  wsb = (char*)d_ws;

    const int xsplit = (ws_size >= OB_FULL_END) ? 1 : 0;
    const int hist   = (ws_size >= OB_HIST_END) ? 1 : 0;

    hipMemsetAsync(d_ws, 0, OB_STATE_END, stream);

    repack_w<<<dim3(G, 3), 256, 0, stream>>>(Wx0, Wh0, 256, 768, G, 1,
        (unsigned short*)(wsb + OB_W0HI), (unsigned short*)(wsb + OB_W0LO));
    repack_w<<<dim3(G, 4), 256, 0, stream>>>(Wx1, Wh1, 512, 1024, G, 1,
        (unsigned short*)(wsb + OB_W1HI), (unsigned short*)(wsb + OB_W1LO));
    repack_w<<<dim3(DOUT, 2), 256, 0, stream>>>(Wfc, Wfc, 512, 512, DOUT, 0,
        (unsigned short*)(wsb + OB_FHI), (unsigned short*)(wsb + OB_FLO));
    repack_bias<<<16, 256, 0, stream>>>(bx0, bh0, bx1, bh1, ws);
    if (xsplit) repack_x<<<2048, 256, 0, stream>>>(x, ws);

    const int kmax = hist ? S : (S + 1);
    for (int k = 0; k <= kmax; ++k) {
        lstm_phase<<<256, 512, 0, stream>>>(x, ws, k, xsplit, hist);
        if (!hist) fc_fallback<<<16, 64, 0, stream>>>(bfc, out, ws, k - 2);
    }
    if (hist) {
        dim3 g(B * S / 32, DOUT / 64);
        fc_split<<<g, 256, 0, stream>>>(bfc, out, ws);
    }
}